// Round 1
// baseline (497.774 us; speedup 1.0000x reference)
//
#include <hip/hip_runtime.h>

#define N_RES 768
#define C_M 256
#define C_Z 128
#define NO_BINS 15
#define Z_ROWS (N_RES * N_RES)        // 589824
#define Z_BLOCKS (Z_ROWS / 16)        // 36864 blocks, 16 rows/block
#define M_BLOCKS (N_RES / 16)         // 48 blocks, 16 rows/block

// ---------------------------------------------------------------------------
// Prep kernel (1 block): build into d_ws
//   wt[b*128 + c]  = w_lin[c*15 + b]   (transposed linear weight, 1920 floats)
//   bias[c]        = be_z[c] + b_lin[c]  (128 floats, at offset 1920)
// ---------------------------------------------------------------------------
__global__ __launch_bounds__(256) void prep_kernel(const float* __restrict__ w_lin,
                                                   const float* __restrict__ b_lin,
                                                   const float* __restrict__ be_z,
                                                   float* __restrict__ ws) {
    const int tid = threadIdx.x;
    for (int idx = tid; idx < NO_BINS * C_Z; idx += 256) {
        const int c = idx / NO_BINS;
        const int b = idx - c * NO_BINS;
        ws[b * C_Z + c] = w_lin[idx];
    }
    if (tid < C_Z) {
        ws[NO_BINS * C_Z + tid] = be_z[tid] + b_lin[tid];
    }
}

// ---------------------------------------------------------------------------
// Fused kernel: blocks [0, Z_BLOCKS) do z_update, blocks [Z_BLOCKS, +M_BLOCKS)
// do m_update. 16 lanes own one row; each lane holds 2 (z) or 4 (m) float4s.
// Two/four independent global loads per thread -> 2-4x memory-level
// parallelism vs the old 1-load layout; reduction is 4 shuffle levels (8 DS
// ops) instead of 5 (10). No LDS, no barriers.
// ---------------------------------------------------------------------------
__global__ __launch_bounds__(256) void fused_kernel(const float* __restrict__ z,
                                                    const float* __restrict__ x,
                                                    const float* __restrict__ ws,
                                                    const float* __restrict__ g_z,
                                                    const float* __restrict__ m,
                                                    const float* __restrict__ g_m,
                                                    const float* __restrict__ be_m,
                                                    float* __restrict__ out_z,
                                                    float* __restrict__ out_m) {
    const int tid = threadIdx.x;
    const int grp = tid >> 4;             // 0..15 : which row within block
    const int hl  = tid & 15;             // lane within 16-lane group

    if (blockIdx.x < Z_BLOCKS) {
        // ------------------------- z path --------------------------------
        const int row = blockIdx.x * 16 + grp;       // < 589824
        const int i   = row / N_RES;
        const int j   = row - i * N_RES;

        // squared distance, exact IEEE order (no fma contraction) to match
        // reference binning — DO NOT TOUCH
        const float dx = x[i * 3 + 0] - x[j * 3 + 0];
        const float dy = x[i * 3 + 1] - x[j * 3 + 1];
        const float dz = x[i * 3 + 2] - x[j * 3 + 2];
        const float d2 = __fadd_rn(__fadd_rn(__fmul_rn(dx, dx), __fmul_rn(dy, dy)),
                                   __fmul_rn(dz, dz));

        // one-hot bin: b active iff sq_bins[b] < d2 < upper[b]
        int bin = -1;
#pragma unroll
        for (int b = 0; b < NO_BINS; b++) {
            const float lov = 3.25f + 1.25f * (float)b;
            const float hiv = 3.25f + 1.25f * (float)(b + 1);
            const float lo  = lov * lov;                       // fp32 const-folded
            const float hi  = (b < NO_BINS - 1) ? hiv * hiv : 1e8f;
            if (d2 > lo && d2 < hi) bin = b;
        }

        // two independent 16B loads per lane covering the 128-ch row
        const float4* zr = (const float4*)(z + (size_t)row * C_Z);
        const float4 v0 = zr[hl];
        const float4 v1 = zr[hl + 16];

        float s  = ((v0.x + v0.y) + (v0.z + v0.w)) + ((v1.x + v1.y) + (v1.z + v1.w));
        float ss = (v0.x * v0.x + v0.y * v0.y + v0.z * v0.z + v0.w * v0.w)
                 + (v1.x * v1.x + v1.y * v1.y + v1.z * v1.z + v1.w * v1.w);
#pragma unroll
        for (int off = 8; off >= 1; off >>= 1) {    // stays within 16-lane group
            s  += __shfl_xor(s,  off);
            ss += __shfl_xor(ss, off);
        }
        const float mu  = s * (1.0f / C_Z);
        const float var = ss * (1.0f / C_Z) - mu * mu;
        const float rs  = rsqrtf(var + 1e-5f);

        const float4 gv0 = ((const float4*)g_z)[hl];
        const float4 gv1 = ((const float4*)g_z)[hl + 16];
        const float4 bv0 = ((const float4*)(ws + NO_BINS * C_Z))[hl];
        const float4 bv1 = ((const float4*)(ws + NO_BINS * C_Z))[hl + 16];
        float4 wv0 = make_float4(0.f, 0.f, 0.f, 0.f);
        float4 wv1 = make_float4(0.f, 0.f, 0.f, 0.f);
        if (bin >= 0) {
            wv0 = ((const float4*)(ws + bin * C_Z))[hl];
            wv1 = ((const float4*)(ws + bin * C_Z))[hl + 16];
        }

        float4 o0, o1;
        o0.x = (v0.x - mu) * rs * gv0.x + bv0.x + wv0.x;
        o0.y = (v0.y - mu) * rs * gv0.y + bv0.y + wv0.y;
        o0.z = (v0.z - mu) * rs * gv0.z + bv0.z + wv0.z;
        o0.w = (v0.w - mu) * rs * gv0.w + bv0.w + wv0.w;
        o1.x = (v1.x - mu) * rs * gv1.x + bv1.x + wv1.x;
        o1.y = (v1.y - mu) * rs * gv1.y + bv1.y + wv1.y;
        o1.z = (v1.z - mu) * rs * gv1.z + bv1.z + wv1.z;
        o1.w = (v1.w - mu) * rs * gv1.w + bv1.w + wv1.w;

        float4* orow = (float4*)(out_z + (size_t)row * C_Z);
        orow[hl]      = o0;
        orow[hl + 16] = o1;
    } else {
        // ------------------------- m path --------------------------------
        const int row = (blockIdx.x - Z_BLOCKS) * 16 + grp;   // < 768
        const float4* mr = (const float4*)(m + row * C_M);
        const float4 v0 = mr[hl];
        const float4 v1 = mr[hl + 16];
        const float4 v2 = mr[hl + 32];
        const float4 v3 = mr[hl + 48];

        float s  = ((v0.x + v0.y) + (v0.z + v0.w)) + ((v1.x + v1.y) + (v1.z + v1.w))
                 + ((v2.x + v2.y) + (v2.z + v2.w)) + ((v3.x + v3.y) + (v3.z + v3.w));
        float ss = (v0.x * v0.x + v0.y * v0.y + v0.z * v0.z + v0.w * v0.w)
                 + (v1.x * v1.x + v1.y * v1.y + v1.z * v1.z + v1.w * v1.w)
                 + (v2.x * v2.x + v2.y * v2.y + v2.z * v2.z + v2.w * v2.w)
                 + (v3.x * v3.x + v3.y * v3.y + v3.z * v3.z + v3.w * v3.w);
#pragma unroll
        for (int off = 8; off >= 1; off >>= 1) {
            s  += __shfl_xor(s,  off);
            ss += __shfl_xor(ss, off);
        }
        const float mu  = s * (1.0f / C_M);
        const float var = ss * (1.0f / C_M) - mu * mu;
        const float rs  = rsqrtf(var + 1e-5f);

        const float4 g0 = ((const float4*)g_m)[hl];
        const float4 g1 = ((const float4*)g_m)[hl + 16];
        const float4 g2 = ((const float4*)g_m)[hl + 32];
        const float4 g3 = ((const float4*)g_m)[hl + 48];
        const float4 b0 = ((const float4*)be_m)[hl];
        const float4 b1 = ((const float4*)be_m)[hl + 16];
        const float4 b2 = ((const float4*)be_m)[hl + 32];
        const float4 b3 = ((const float4*)be_m)[hl + 48];

        float4 o0, o1, o2, o3;
        o0.x = (v0.x - mu) * rs * g0.x + b0.x;
        o0.y = (v0.y - mu) * rs * g0.y + b0.y;
        o0.z = (v0.z - mu) * rs * g0.z + b0.z;
        o0.w = (v0.w - mu) * rs * g0.w + b0.w;
        o1.x = (v1.x - mu) * rs * g1.x + b1.x;
        o1.y = (v1.y - mu) * rs * g1.y + b1.y;
        o1.z = (v1.z - mu) * rs * g1.z + b1.z;
        o1.w = (v1.w - mu) * rs * g1.w + b1.w;
        o2.x = (v2.x - mu) * rs * g2.x + b2.x;
        o2.y = (v2.y - mu) * rs * g2.y + b2.y;
        o2.z = (v2.z - mu) * rs * g2.z + b2.z;
        o2.w = (v2.w - mu) * rs * g2.w + b2.w;
        o3.x = (v3.x - mu) * rs * g3.x + b3.x;
        o3.y = (v3.y - mu) * rs * g3.y + b3.y;
        o3.z = (v3.z - mu) * rs * g3.z + b3.z;
        o3.w = (v3.w - mu) * rs * g3.w + b3.w;

        float4* orow = (float4*)(out_m + row * C_M);
        orow[hl]      = o0;
        orow[hl + 16] = o1;
        orow[hl + 32] = o2;
        orow[hl + 48] = o3;
    }
}

extern "C" void kernel_launch(void* const* d_in, const int* in_sizes, int n_in,
                              void* d_out, int out_size, void* d_ws, size_t ws_size,
                              hipStream_t stream) {
    const float* m     = (const float*)d_in[0];
    const float* z     = (const float*)d_in[1];
    const float* x     = (const float*)d_in[2];
    const float* w_lin = (const float*)d_in[3];
    const float* b_lin = (const float*)d_in[4];
    const float* g_m   = (const float*)d_in[5];
    const float* be_m  = (const float*)d_in[6];
    const float* g_z   = (const float*)d_in[7];
    const float* be_z  = (const float*)d_in[8];

    float* out   = (float*)d_out;
    float* out_m = out;                       // [768*256]
    float* out_z = out + N_RES * C_M;         // [768*768*128]
    float* ws    = (float*)d_ws;              // 1920 + 128 floats = 8192 B

    prep_kernel<<<1, 256, 0, stream>>>(w_lin, b_lin, be_z, ws);
    fused_kernel<<<Z_BLOCKS + M_BLOCKS, 256, 0, stream>>>(z, x, ws, g_z,
                                                          m, g_m, be_m,
                                                          out_z, out_m);
}